// Round 10
// baseline (265.250 us; speedup 1.0000x reference)
//
#include <hip/hip_runtime.h>

typedef unsigned short u16;
typedef unsigned int u32;
typedef unsigned long long u64;
typedef __attribute__((ext_vector_type(8))) short bf16x8;   // 8 bf16 = 4 VGPRs
typedef __attribute__((ext_vector_type(4))) float f32x4;
typedef __attribute__((ext_vector_type(2))) unsigned int u32x2;
typedef __attribute__((ext_vector_type(4))) unsigned int u32x4;

#define MFMA16(A, B, C) __builtin_amdgcn_mfma_f32_16x16x32_bf16(A, B, C, 0, 0, 0)

__device__ __forceinline__ u16 f2bf(float f) {
  union { float f; unsigned u; } x; x.f = f;
  unsigned r = x.u + 0x7fffu + ((x.u >> 16) & 1u);   // RNE
  return (u16)(r >> 16);
}

// pack two fp32 -> two bf16 in one dword (round-half-up): lo16=a, hi16=b
__device__ __forceinline__ u32 pack_bf2(float a, float b) {
  const u32 ua = __builtin_bit_cast(u32, a) + 0x8000u;
  const u32 ub = __builtin_bit_cast(u32, b) + 0x8000u;
  return __builtin_amdgcn_perm(ub, ua, 0x07060302u);  // bytes: [a2,a3,b2,b3]
}

// async global->LDS, 16B/lane; dest must be wave-uniform base + lane*16
__device__ __forceinline__ void gload_lds16(const u16* g, u16* l) {
  __builtin_amdgcn_global_load_lds((const __attribute__((address_space(1))) void*)g,
                                   (__attribute__((address_space(3))) void*)l,
                                   16, 0, 0);
}

// ---------------------------------------------------------------------------
// fp32 -> bf16 for x, Wq|Wk|Wv (concat -> Wqkvb), Wo; last block packs mask.
// ---------------------------------------------------------------------------
__global__ __launch_bounds__(256) void cvt_all(const float* __restrict__ x,
                                               const float* __restrict__ Wq,
                                               const float* __restrict__ Wk,
                                               const float* __restrict__ Wv,
                                               const float* __restrict__ Wo,
                                               const int* __restrict__ mask,
                                               u16* __restrict__ xb,
                                               u16* __restrict__ Wqkvb,
                                               u16* __restrict__ Wob,
                                               u32* __restrict__ mbits,
                                               int NE, int NW, int NB) {
  if ((int)blockIdx.x == NB) {              // mask-pack block
    const int t = threadIdx.x;
    if (t < 128) {
      const int* m = mask + t * 32;
      u32 w = 0;
#pragma unroll
      for (int j = 0; j < 32; j++) w |= (m[j] != 0 ? 1u : 0u) << j;
      mbits[t] = w;
    }
    return;
  }
  const int e = (blockIdx.x * 256 + threadIdx.x) * 8;
  const float* s;
  u16* d;
  if (e < NE) { s = x + e; d = xb + e; }
  else {
    int f = e - NE;
    if (f < 3 * NW) {
      d = Wqkvb + f;
      s = (f < NW) ? Wq + f : (f < 2 * NW) ? Wk + (f - NW) : Wv + (f - 2 * NW);
    } else { f -= 3 * NW; s = Wo + f; d = Wob + f; }
  }
  const float4 a = *(const float4*)s;
  const float4 b = *(const float4*)(s + 4);
  bf16x8 o;
  o[0] = (short)f2bf(a.x); o[1] = (short)f2bf(a.y);
  o[2] = (short)f2bf(a.z); o[3] = (short)f2bf(a.w);
  o[4] = (short)f2bf(b.x); o[5] = (short)f2bf(b.y);
  o[6] = (short)f2bf(b.z); o[7] = (short)f2bf(b.w);
  *(bf16x8*)d = o;
}

// ---------------------------------------------------------------------------
// Fused QKV NT GEMM: [4096,1024] @ [3072,1024]^T. 128x128 tile, BK=64
// (half the barriers of BK=32), global_load_lds x16 staging, XOR-chunk
// swizzle (8 sub-chunks/row). Q,K bf16 row-major; V -> per-head-transposed
// Vt, keys 4-way interleaved per 64-group (matches attn's P layout).
// ---------------------------------------------------------------------------
__global__ __launch_bounds__(256) void gemm_qkv(const u16* __restrict__ A,
                                                const u16* __restrict__ B,
                                                u16* __restrict__ Qo,
                                                u16* __restrict__ Ko,
                                                u16* __restrict__ Vto,
                                                int M, int N, int K) {
  __shared__ alignas(16) u16 As[128 * 64];   // 16 KB, chunk-linear + XOR col
  __shared__ alignas(16) u16 Bs[128 * 64];   // 16 KB
  const int t = threadIdx.x;
  const int lane = t & 63, wave = t >> 6;
  const int quad = lane >> 4, l16 = lane & 15;
  const int m0 = blockIdx.y * 128, n0 = blockIdx.x * 128;
  const int wm = (wave >> 1) * 64, wn = (wave & 1) * 64;
  const int sx = l16 & 7;

  f32x4 acc[4][4] = {};

  for (int kk = 0; kk < K; kk += 64) {
#pragma unroll
    for (int i = 0; i < 4; i++) {
      const int c = t + i * 256;              // chunk id in [0,1024)
      const int row = c >> 3, sub = c & 7;
      const int col = ((sub ^ (row & 7)) * 8);
      gload_lds16(A + (size_t)(m0 + row) * K + kk + col, As + (size_t)c * 8);
      gload_lds16(B + (size_t)(n0 + row) * K + kk + col, Bs + (size_t)c * 8);
    }
    __syncthreads();

#pragma unroll
    for (int ks = 0; ks < 2; ks++) {
      bf16x8 af[4], bfr[4];
#pragma unroll
      for (int i = 0; i < 4; i++)
        af[i] = *(const bf16x8*)(As + (wm + i * 16 + l16) * 64 +
                                 ((ks * 4 + quad) ^ sx) * 8);
#pragma unroll
      for (int j = 0; j < 4; j++)
        bfr[j] = *(const bf16x8*)(Bs + (wn + j * 16 + l16) * 64 +
                                  ((ks * 4 + quad) ^ sx) * 8);
#pragma unroll
      for (int i = 0; i < 4; i++)
#pragma unroll
        for (int j = 0; j < 4; j++)
          acc[i][j] = MFMA16(af[i], bfr[j], acc[i][j]);
    }
    __syncthreads();
  }

  const int G = ((m0 + wm) & 2047) >> 6;
#pragma unroll
  for (int j = 0; j < 4; j++) {
    const int col = n0 + wn + j * 16 + l16;
    if (col < 1024) {
#pragma unroll
      for (int i = 0; i < 4; i++)
#pragma unroll
        for (int r = 0; r < 4; r++)
          Qo[(size_t)(m0 + wm + i * 16 + quad * 4 + r) * 1024 + col] =
              f2bf(acc[i][j][r]);
    } else if (col < 2048) {
#pragma unroll
      for (int i = 0; i < 4; i++)
#pragma unroll
        for (int r = 0; r < 4; r++)
          Ko[(size_t)(m0 + wm + i * 16 + quad * 4 + r) * 1024 + (col - 1024)] =
              f2bf(acc[i][j][r]);
    } else {
      u16* base = Vto + ((size_t)(m0 >> 11) * 1024 + (col - 2048)) * 2048 + G * 64;
#pragma unroll
      for (int r = 0; r < 4; r++) {
        u32x2 v;
        v.x = pack_bf2(acc[0][j][r], acc[1][j][r]);
        v.y = pack_bf2(acc[2][j][r], acc[3][j][r]);
        *(u32x2*)(base + 4 * (quad * 4 + r)) = v;
      }
    }
  }
}

// ---------------------------------------------------------------------------
// Out GEMM with FUSED split-K merge: C[4096,1024] fp32 =
//   merge(OP0,OP1,Lp) @ Wo^T.  A-tile staged manually: (OP0+OP1)*inv ->
//   bf16 pack -> ds_write_b128 (chunk-XOR layout). 128x64 tile, BK=64
//   (aligned with 64-wide heads: column block kk..kk+63 = head kk>>6).
// ---------------------------------------------------------------------------
__global__ __launch_bounds__(256) void gemm_out(const float* __restrict__ OP0,
                                                const float* __restrict__ OP1,
                                                const float* __restrict__ Lp,
                                                const u16* __restrict__ Bw,
                                                float* __restrict__ C,
                                                int M, int N, int K) {
  __shared__ alignas(16) u16 As[128 * 64];   // 16 KB
  __shared__ alignas(16) u16 Bs[64 * 64];    // 8 KB
  const int t = threadIdx.x;
  const int lane = t & 63, wave = t >> 6;
  const int quad = lane >> 4, l16 = lane & 15;
  const int m0 = blockIdx.y * 128, n0 = blockIdx.x * 64;
  const int wm = (wave >> 1) * 64, wn = (wave & 1) * 32;
  const int sx = l16 & 7;

  // A staging: thread t -> row = t>>1, half = t&1 (d 0..31 / 32..63)
  const int arow = t >> 1, ah = t & 1;
  const int bq16 = ((m0 + arow) >> 11) * 16;     // b*16
  const int qq = (m0 + arow) & 2047;

  f32x4 acc[4][2] = {};

  for (int kk = 0; kk < 1024; kk += 64) {
    const int h = kk >> 6;
    const size_t r64 = (((size_t)(bq16 + h)) << 11) + qq;
    const float inv = 1.0f / (Lp[r64] + Lp[65536 + r64]);
    const float* p0 = OP0 + r64 * 64 + ah * 32;
    const float* p1 = OP1 + r64 * 64 + ah * 32;
#pragma unroll
    for (int j = 0; j < 4; j++) {
      const float4 a  = *(const float4*)(p0 + j * 8);
      const float4 a2 = *(const float4*)(p0 + j * 8 + 4);
      const float4 c  = *(const float4*)(p1 + j * 8);
      const float4 c2 = *(const float4*)(p1 + j * 8 + 4);
      u32x4 w;
      w.x = pack_bf2((a.x + c.x) * inv, (a.y + c.y) * inv);
      w.y = pack_bf2((a.z + c.z) * inv, (a.w + c.w) * inv);
      w.z = pack_bf2((a2.x + c2.x) * inv, (a2.y + c2.y) * inv);
      w.w = pack_bf2((a2.z + c2.z) * inv, (a2.w + c2.w) * inv);
      const int sub = ah * 4 + j;
      *(u32x4*)(As + ((size_t)arow * 8 + (sub ^ (arow & 7))) * 8) = w;
    }
    // B staging via DMA (plain bf16 weights)
#pragma unroll
    for (int i = 0; i < 2; i++) {
      const int c = t + i * 256;               // chunk in [0,512)
      const int row = c >> 3, sub = c & 7;
      gload_lds16(Bw + (size_t)(n0 + row) * K + kk + ((sub ^ (row & 7)) * 8),
                  Bs + (size_t)c * 8);
    }
    __syncthreads();

#pragma unroll
    for (int ks = 0; ks < 2; ks++) {
      bf16x8 af[4], bfr[2];
#pragma unroll
      for (int i = 0; i < 4; i++)
        af[i] = *(const bf16x8*)(As + (wm + i * 16 + l16) * 64 +
                                 ((ks * 4 + quad) ^ sx) * 8);
#pragma unroll
      for (int j = 0; j < 2; j++)
        bfr[j] = *(const bf16x8*)(Bs + (wn + j * 16 + l16) * 64 +
                                  ((ks * 4 + quad) ^ sx) * 8);
#pragma unroll
      for (int i = 0; i < 4; i++)
#pragma unroll
        for (int j = 0; j < 2; j++)
          acc[i][j] = MFMA16(af[i], bfr[j], acc[i][j]);
    }
    __syncthreads();
  }

#pragma unroll
  for (int i = 0; i < 4; i++)
#pragma unroll
    for (int j = 0; j < 2; j++)
#pragma unroll
      for (int r = 0; r < 4; r++)
        C[(size_t)(m0 + wm + i * 16 + quad * 4 + r) * N + n0 + wn + j * 16 + l16] =
            acc[i][j][r];
}

// ---------------------------------------------------------------------------
// Flash attention v7 (unchanged from round 9): grid split-K x2, 256 thr,
// 4 waves x 32 q, raw v_exp_f32, 40 KB LDS, XOR-swizzled staging.
// ---------------------------------------------------------------------------
__global__ __launch_bounds__(256) void attn_fwd(const u16* __restrict__ Q,
                                                const u16* __restrict__ Kb_,
                                                const u16* __restrict__ Vt,
                                                const u32* __restrict__ mbits,
                                                float* __restrict__ OP0,
                                                float* __restrict__ OP1,
                                                float* __restrict__ Lp) {
  constexpr int S = 2048, E = 1024;
  __shared__ alignas(16) u16 Ks[2][64 * 64];   // 16 KB
  __shared__ alignas(16) u16 Vs[2][64 * 64];   // 16 KB
  __shared__ alignas(16) u32 Pl[4][16 * 32];   // 8 KB
  const int t = threadIdx.x;
  const int lane = t & 63, wave = t >> 6;
  const int quad = lane >> 4, l16 = lane & 15;
  const int bh = blockIdx.y, b = bh >> 4, h = bh & 15;
  const int sp = blockIdx.z;
  const int kbase0 = sp * 1024;
  const int q0 = blockIdx.x * 128 + wave * 32;

  const int c0 = t, c1 = t + 256;
  const int kr0 = c0 >> 3, kr1 = c1 >> 3;
  const int kcol0 = ((c0 & 7) ^ (kr0 & 7)) * 8;
  const int kcol1 = ((c1 & 7) ^ (kr1 & 7)) * 8;
  const u16* kP0 = Kb_ + (size_t)(b * S + kbase0 + kr0) * E + h * 64 + kcol0;
  const u16* kP1 = Kb_ + (size_t)(b * S + kbase0 + kr1) * E + h * 64 + kcol1;
  const u16* vbase = Vt + (size_t)(b * 16 + h) * 64 * S + kbase0;
  const u16* vP0 = vbase + (size_t)kr0 * S + kcol0;
  const u16* vP1 = vbase + (size_t)kr1 * S + kcol1;

  bf16x8 aq[2][2];
#pragma unroll
  for (int qt = 0; qt < 2; qt++) {
    const u16* qp = Q + ((size_t)(b * S) + q0 + qt * 16 + l16) * E + h * 64;
    aq[qt][0] = *(const bf16x8*)(qp + quad * 8);
    aq[qt][1] = *(const bf16x8*)(qp + 32 + quad * 8);
  }

  const u32* mb = mbits + b * 64;
  const int sx = l16 & 7;
  const int pkey = l16 & 14;

  float lr[2][4] = {};
  f32x4 accO[2][4] = {};
  const float fq0 = (float)(q0 + quad * 4 - 2047);

  const float K1 = 0.125f * 1.44269504f;
  const float K2 = 2.44140625e-4f * 1.44269504f;
  const float K3 = -8.0f * 1.44269504f;

  gload_lds16(kP0, Ks[0] + c0 * 8);
  gload_lds16(kP1, Ks[0] + c1 * 8);
  gload_lds16(vP0, Vs[0] + c0 * 8);
  gload_lds16(vP1, Vs[0] + c1 * 8);
  __syncthreads();

  int buf = 0;
  for (int kc = 0; kc < 1024; kc += 64) {
    if (kc + 64 < 1024) {
      const int kn = kc + 64;
      gload_lds16(kP0 + (size_t)kn * E, Ks[buf ^ 1] + c0 * 8);
      gload_lds16(kP1 + (size_t)kn * E, Ks[buf ^ 1] + c1 * 8);
      gload_lds16(vP0 + kn, Vs[buf ^ 1] + c0 * 8);
      gload_lds16(vP1 + kn, Vs[buf ^ 1] + c1 * 8);
    }
    const u16* ks = Ks[buf];
    const u16* vs = Vs[buf];
    u32* pl = Pl[wave];

    bf16x8 bk[4][2];
#pragma unroll
    for (int T = 0; T < 4; T++)
#pragma unroll
      for (int dh = 0; dh < 2; dh++)
        bk[T][dh] = *(const bf16x8*)(ks + (T * 16 + l16) * 64 +
                                     ((dh * 4 + quad) ^ sx) * 8);

    f32x4 s[2][4] = {};
#pragma unroll
    for (int qt = 0; qt < 2; qt++)
#pragma unroll
      for (int T = 0; T < 4; T++) {
        s[qt][T] = MFMA16(aq[qt][0], bk[T][0], s[qt][T]);
        s[qt][T] = MFMA16(aq[qt][1], bk[T][1], s[qt][T]);
      }

    const int kabs = kbase0 + kc;
    const u64 mw = *(const u64*)(mb + (kabs >> 5));
    const u32 mlo = (u32)mw, mhi = (u32)(mw >> 32);
    const int mk0 = (mlo >> l16) & 1, mk1 = (mlo >> (l16 + 16)) & 1;
    const int mk2 = (mhi >> l16) & 1, mk3 = (mhi >> (l16 + 16)) & 1;
    const float kl = (float)(kabs + l16);

    u32x2 pk1[4];
#pragma unroll
    for (int qt = 0; qt < 2; qt++)
#pragma unroll
      for (int r = 0; r < 4; r++) {
        const float fb = kl + fq0 + (float)(qt * 16 + r);
        const float e0 = fmaf(fabsf(fb), -K2, fmaf(s[qt][0][r], K1, K3));
        const float e1 = fmaf(fabsf(fb + 16.f), -K2, fmaf(s[qt][1][r], K1, K3));
        const float e2 = fmaf(fabsf(fb + 32.f), -K2, fmaf(s[qt][2][r], K1, K3));
        const float e3 = fmaf(fabsf(fb + 48.f), -K2, fmaf(s[qt][3][r], K1, K3));
        const float p0 = mk0 ? 0.f : __builtin_amdgcn_exp2f(e0);
        const float p1 = mk1 ? 0.f : __builtin_amdgcn_exp2f(e1);
        const float p2 = mk2 ? 0.f : __builtin_amdgcn_exp2f(e2);
        const float p3 = mk3 ? 0.f : __builtin_amdgcn_exp2f(e3);
        lr[qt][r] += (p0 + p1) + (p2 + p3);
        u32x2 v;
        v.x = pack_bf2(p0, p1);
        v.y = pack_bf2(p2, p3);
        if (qt == 0) {
          const int m = quad * 4 + r;
          *(u32x2*)(pl + m * 32 + 2 * (l16 ^ (m & 14))) = v;
        } else {
          pk1[r] = v;
        }
      }

    bf16x8 bv[2][4];
#pragma unroll
    for (int kst = 0; kst < 2; kst++)
#pragma unroll
      for (int tt = 0; tt < 4; tt++)
        bv[kst][tt] = *(const bf16x8*)(vs + (tt * 16 + l16) * 64 +
                                       ((kst * 4 + quad) ^ sx) * 8);

    asm volatile("s_waitcnt lgkmcnt(0)" ::: "memory");
    bf16x8 ap0[2];
#pragma unroll
    for (int kst = 0; kst < 2; kst++)
      ap0[kst] = *(const bf16x8*)(pl + l16 * 32 + 2 * ((kst * 8 + 2 * quad) ^ pkey));
#pragma unroll
    for (int kst = 0; kst < 2; kst++)
#pragma unroll
      for (int tt = 0; tt < 4; tt++)
        accO[0][tt] = MFMA16(ap0[kst], bv[kst][tt], accO[0][tt]);

    asm volatile("" ::: "memory");
#pragma unroll
    for (int r = 0; r < 4; r++) {
      const int m = quad * 4 + r;
      *(u32x2*)(pl + m * 32 + 2 * (l16 ^ (m & 14))) = pk1[r];
    }
    asm volatile("s_waitcnt lgkmcnt(0)" ::: "memory");
    bf16x8 ap1[2];
#pragma unroll
    for (int kst = 0; kst < 2; kst++)
      ap1[kst] = *(const bf16x8*)(pl + l16 * 32 + 2 * ((kst * 8 + 2 * quad) ^ pkey));
#pragma unroll
    for (int kst = 0; kst < 2; kst++)
#pragma unroll
      for (int tt = 0; tt < 4; tt++)
        accO[1][tt] = MFMA16(ap1[kst], bv[kst][tt], accO[1][tt]);

    __syncthreads();
    buf ^= 1;
  }

  float* OP = sp ? OP1 : OP0;
#pragma unroll
  for (int qt = 0; qt < 2; qt++)
#pragma unroll
    for (int r = 0; r < 4; r++) {
      float l = lr[qt][r];
      l += __shfl_xor(l, 1);
      l += __shfl_xor(l, 2);
      l += __shfl_xor(l, 4);
      l += __shfl_xor(l, 8);
      const int qg = q0 + qt * 16 + quad * 4 + r;
      const size_t row = ((size_t)bh << 11) + qg;
      float* orow = OP + row * 64;
#pragma unroll
      for (int tt = 0; tt < 4; tt++) orow[tt * 16 + l16] = accO[qt][tt][r];
      if (l16 == 0) Lp[((size_t)sp << 16) + row] = l;
    }
}

// ---------------------------------------------------------------------------
extern "C" void kernel_launch(void* const* d_in, const int* in_sizes, int n_in,
                              void* d_out, int out_size, void* d_ws, size_t ws_size,
                              hipStream_t stream) {
  const float* x  = (const float*)d_in[0];
  const float* Wq = (const float*)d_in[1];
  const float* Wk = (const float*)d_in[2];
  const float* Wv = (const float*)d_in[3];
  const float* Wo = (const float*)d_in[4];
  const int* mask = (const int*)d_in[5];

  const int M = 4096, N = 1024, K = 1024;
  const int NE = M * N, NW = N * K;
  const int NB = (NE + 4 * NW) / 2048;

  u16* xb    = (u16*)d_ws;
  u16* Wqkvb = xb + NE;
  u16* Wob   = Wqkvb + (size_t)3 * NW;
  u16* Qb    = Wob + NW;
  u16* Kb    = Qb + NE;
  u16* Vt    = Kb + NE;
  u32* mbits = (u32*)(Vt + NE);              // 128 words
  float* OP0 = (float*)(mbits + 128);        // split-0 partials (16.8 MB, in ws:
  float* OP1 = OP0 + (size_t)65536 * 64;     //  gemm_out reads it while writing d_out)
  float* Lp  = OP1 + (size_t)65536 * 64;     // 2 x 65536 row-sums

  cvt_all<<<NB + 1, 256, 0, stream>>>(x, Wq, Wk, Wv, Wo, mask,
                                      xb, Wqkvb, Wob, mbits, NE, NW, NB);

  gemm_qkv<<<dim3(3072 / 128, M / 128), 256, 0, stream>>>(
      xb, Wqkvb, Qb, Kb, Vt, M, 3072, K);
  attn_fwd<<<dim3(16, 32, 2), 256, 0, stream>>>(Qb, Kb, Vt, mbits,
                                                OP0, OP1, Lp);
  gemm_out<<<dim3(N / 64, M / 128), 256, 0, stream>>>(
      OP0, OP1, Lp, Wob, (float*)d_out, M, N, K);
}

// Round 11
// 212.191 us; speedup vs baseline: 1.2501x; 1.2501x over previous
//
#include <hip/hip_runtime.h>

typedef unsigned short u16;
typedef unsigned int u32;
typedef unsigned long long u64;
typedef __attribute__((ext_vector_type(8))) short bf16x8;   // 8 bf16 = 4 VGPRs
typedef __attribute__((ext_vector_type(4))) float f32x4;
typedef __attribute__((ext_vector_type(2))) unsigned int u32x2;

#define MFMA16(A, B, C) __builtin_amdgcn_mfma_f32_16x16x32_bf16(A, B, C, 0, 0, 0)

__device__ __forceinline__ u16 f2bf(float f) {
  union { float f; unsigned u; } x; x.f = f;
  unsigned r = x.u + 0x7fffu + ((x.u >> 16) & 1u);   // RNE
  return (u16)(r >> 16);
}

// pack two fp32 -> two bf16 in one dword (round-half-up): lo16=a, hi16=b
__device__ __forceinline__ u32 pack_bf2(float a, float b) {
  const u32 ua = __builtin_bit_cast(u32, a) + 0x8000u;
  const u32 ub = __builtin_bit_cast(u32, b) + 0x8000u;
  return __builtin_amdgcn_perm(ub, ua, 0x07060302u);  // bytes: [a2,a3,b2,b3]
}

// async global->LDS, 16B/lane; dest must be wave-uniform base + lane*16
__device__ __forceinline__ void gload_lds16(const u16* g, u16* l) {
  __builtin_amdgcn_global_load_lds((const __attribute__((address_space(1))) void*)g,
                                   (__attribute__((address_space(3))) void*)l,
                                   16, 0, 0);
}

// ---------------------------------------------------------------------------
// fp32 -> bf16 for x, Wq|Wk|Wv (concat -> Wqkvb), Wo; last block packs mask.
// ---------------------------------------------------------------------------
__global__ __launch_bounds__(256) void cvt_all(const float* __restrict__ x,
                                               const float* __restrict__ Wq,
                                               const float* __restrict__ Wk,
                                               const float* __restrict__ Wv,
                                               const float* __restrict__ Wo,
                                               const int* __restrict__ mask,
                                               u16* __restrict__ xb,
                                               u16* __restrict__ Wqkvb,
                                               u16* __restrict__ Wob,
                                               u32* __restrict__ mbits,
                                               int NE, int NW, int NB) {
  if ((int)blockIdx.x == NB) {              // mask-pack block
    const int t = threadIdx.x;
    if (t < 128) {
      const int* m = mask + t * 32;
      u32 w = 0;
#pragma unroll
      for (int j = 0; j < 32; j++) w |= (m[j] != 0 ? 1u : 0u) << j;
      mbits[t] = w;
    }
    return;
  }
  const int e = (blockIdx.x * 256 + threadIdx.x) * 8;
  const float* s;
  u16* d;
  if (e < NE) { s = x + e; d = xb + e; }
  else {
    int f = e - NE;
    if (f < 3 * NW) {
      d = Wqkvb + f;
      s = (f < NW) ? Wq + f : (f < 2 * NW) ? Wk + (f - NW) : Wv + (f - 2 * NW);
    } else { f -= 3 * NW; s = Wo + f; d = Wob + f; }
  }
  const float4 a = *(const float4*)s;
  const float4 b = *(const float4*)(s + 4);
  bf16x8 o;
  o[0] = (short)f2bf(a.x); o[1] = (short)f2bf(a.y);
  o[2] = (short)f2bf(a.z); o[3] = (short)f2bf(a.w);
  o[4] = (short)f2bf(b.x); o[5] = (short)f2bf(b.y);
  o[6] = (short)f2bf(b.z); o[7] = (short)f2bf(b.w);
  *(bf16x8*)d = o;
}

// ---------------------------------------------------------------------------
// Fused QKV NT GEMM: [4096,1024] @ [3072,1024]^T. 128x128 tile, BK=64
// (half the barriers of BK=32), global_load_lds x16 staging, XOR-chunk
// swizzle (8 sub-chunks/row). Q,K bf16 row-major; V -> per-head-transposed
// Vt, keys 4-way interleaved per 64-group (matches attn's P layout).
// ---------------------------------------------------------------------------
__global__ __launch_bounds__(256) void gemm_qkv(const u16* __restrict__ A,
                                                const u16* __restrict__ B,
                                                u16* __restrict__ Qo,
                                                u16* __restrict__ Ko,
                                                u16* __restrict__ Vto,
                                                int M, int N, int K) {
  __shared__ alignas(16) u16 As[128 * 64];   // 16 KB, chunk-linear + XOR col
  __shared__ alignas(16) u16 Bs[128 * 64];   // 16 KB
  const int t = threadIdx.x;
  const int lane = t & 63, wave = t >> 6;
  const int quad = lane >> 4, l16 = lane & 15;
  const int m0 = blockIdx.y * 128, n0 = blockIdx.x * 128;
  const int wm = (wave >> 1) * 64, wn = (wave & 1) * 64;
  const int sx = l16 & 7;

  f32x4 acc[4][4] = {};

  for (int kk = 0; kk < K; kk += 64) {
#pragma unroll
    for (int i = 0; i < 4; i++) {
      const int c = t + i * 256;              // chunk id in [0,1024)
      const int row = c >> 3, sub = c & 7;
      const int col = ((sub ^ (row & 7)) * 8);
      gload_lds16(A + (size_t)(m0 + row) * K + kk + col, As + (size_t)c * 8);
      gload_lds16(B + (size_t)(n0 + row) * K + kk + col, Bs + (size_t)c * 8);
    }
    __syncthreads();

#pragma unroll
    for (int ks = 0; ks < 2; ks++) {
      bf16x8 af[4], bfr[4];
#pragma unroll
      for (int i = 0; i < 4; i++)
        af[i] = *(const bf16x8*)(As + (wm + i * 16 + l16) * 64 +
                                 ((ks * 4 + quad) ^ sx) * 8);
#pragma unroll
      for (int j = 0; j < 4; j++)
        bfr[j] = *(const bf16x8*)(Bs + (wn + j * 16 + l16) * 64 +
                                  ((ks * 4 + quad) ^ sx) * 8);
#pragma unroll
      for (int i = 0; i < 4; i++)
#pragma unroll
        for (int j = 0; j < 4; j++)
          acc[i][j] = MFMA16(af[i], bfr[j], acc[i][j]);
    }
    __syncthreads();
  }

  const int G = ((m0 + wm) & 2047) >> 6;
#pragma unroll
  for (int j = 0; j < 4; j++) {
    const int col = n0 + wn + j * 16 + l16;
    if (col < 1024) {
#pragma unroll
      for (int i = 0; i < 4; i++)
#pragma unroll
        for (int r = 0; r < 4; r++)
          Qo[(size_t)(m0 + wm + i * 16 + quad * 4 + r) * 1024 + col] =
              f2bf(acc[i][j][r]);
    } else if (col < 2048) {
#pragma unroll
      for (int i = 0; i < 4; i++)
#pragma unroll
        for (int r = 0; r < 4; r++)
          Ko[(size_t)(m0 + wm + i * 16 + quad * 4 + r) * 1024 + (col - 1024)] =
              f2bf(acc[i][j][r]);
    } else {
      u16* base = Vto + ((size_t)(m0 >> 11) * 1024 + (col - 2048)) * 2048 + G * 64;
#pragma unroll
      for (int r = 0; r < 4; r++) {
        u32x2 v;
        v.x = pack_bf2(acc[0][j][r], acc[1][j][r]);
        v.y = pack_bf2(acc[2][j][r], acc[3][j][r]);
        *(u32x2*)(base + 4 * (quad * 4 + r)) = v;
      }
    }
  }
}

// ---------------------------------------------------------------------------
// Out GEMM (unfused, DMA-staged): C[4096,1024] fp32 = Ao @ Wo^T.
// 128x64 tile, BK=64, global_load_lds x16 + XOR-chunk swizzle.
// ---------------------------------------------------------------------------
__global__ __launch_bounds__(256) void gemm_out(const u16* __restrict__ A,
                                                const u16* __restrict__ B,
                                                float* __restrict__ C,
                                                int M, int N, int K) {
  __shared__ alignas(16) u16 As[128 * 64];   // 16 KB
  __shared__ alignas(16) u16 Bs[64 * 64];    // 8 KB
  const int t = threadIdx.x;
  const int lane = t & 63, wave = t >> 6;
  const int quad = lane >> 4, l16 = lane & 15;
  const int m0 = blockIdx.y * 128, n0 = blockIdx.x * 64;
  const int wm = (wave >> 1) * 64, wn = (wave & 1) * 32;
  const int sx = l16 & 7;

  f32x4 acc[4][2] = {};

  for (int kk = 0; kk < K; kk += 64) {
#pragma unroll
    for (int i = 0; i < 4; i++) {
      const int c = t + i * 256;              // A chunks [0,1024)
      const int row = c >> 3, sub = c & 7;
      gload_lds16(A + (size_t)(m0 + row) * K + kk + ((sub ^ (row & 7)) * 8),
                  As + (size_t)c * 8);
    }
#pragma unroll
    for (int i = 0; i < 2; i++) {
      const int c = t + i * 256;              // B chunks [0,512)
      const int row = c >> 3, sub = c & 7;
      gload_lds16(B + (size_t)(n0 + row) * K + kk + ((sub ^ (row & 7)) * 8),
                  Bs + (size_t)c * 8);
    }
    __syncthreads();

#pragma unroll
    for (int ks = 0; ks < 2; ks++) {
      bf16x8 af[4], bfr[2];
#pragma unroll
      for (int i = 0; i < 4; i++)
        af[i] = *(const bf16x8*)(As + (wm + i * 16 + l16) * 64 +
                                 ((ks * 4 + quad) ^ sx) * 8);
#pragma unroll
      for (int j = 0; j < 2; j++)
        bfr[j] = *(const bf16x8*)(Bs + (wn + j * 16 + l16) * 64 +
                                  ((ks * 4 + quad) ^ sx) * 8);
#pragma unroll
      for (int i = 0; i < 4; i++)
#pragma unroll
        for (int j = 0; j < 2; j++)
          acc[i][j] = MFMA16(af[i], bfr[j], acc[i][j]);
    }
    __syncthreads();
  }

#pragma unroll
  for (int i = 0; i < 4; i++)
#pragma unroll
    for (int j = 0; j < 2; j++)
#pragma unroll
      for (int r = 0; r < 4; r++)
        C[(size_t)(m0 + wm + i * 16 + quad * 4 + r) * N + n0 + wn + j * 16 + l16] =
            acc[i][j][r];
}

// ---------------------------------------------------------------------------
// Flash attention v7 (unchanged from round 9): grid split-K x2, 256 thr,
// 4 waves x 32 q, raw v_exp_f32, 40 KB LDS, XOR-swizzled staging.
// ---------------------------------------------------------------------------
__global__ __launch_bounds__(256) void attn_fwd(const u16* __restrict__ Q,
                                                const u16* __restrict__ Kb_,
                                                const u16* __restrict__ Vt,
                                                const u32* __restrict__ mbits,
                                                float* __restrict__ OP0,
                                                float* __restrict__ OP1,
                                                float* __restrict__ Lp) {
  constexpr int S = 2048, E = 1024;
  __shared__ alignas(16) u16 Ks[2][64 * 64];   // 16 KB
  __shared__ alignas(16) u16 Vs[2][64 * 64];   // 16 KB
  __shared__ alignas(16) u32 Pl[4][16 * 32];   // 8 KB
  const int t = threadIdx.x;
  const int lane = t & 63, wave = t >> 6;
  const int quad = lane >> 4, l16 = lane & 15;
  const int bh = blockIdx.y, b = bh >> 4, h = bh & 15;
  const int sp = blockIdx.z;
  const int kbase0 = sp * 1024;
  const int q0 = blockIdx.x * 128 + wave * 32;

  const int c0 = t, c1 = t + 256;
  const int kr0 = c0 >> 3, kr1 = c1 >> 3;
  const int kcol0 = ((c0 & 7) ^ (kr0 & 7)) * 8;
  const int kcol1 = ((c1 & 7) ^ (kr1 & 7)) * 8;
  const u16* kP0 = Kb_ + (size_t)(b * S + kbase0 + kr0) * E + h * 64 + kcol0;
  const u16* kP1 = Kb_ + (size_t)(b * S + kbase0 + kr1) * E + h * 64 + kcol1;
  const u16* vbase = Vt + (size_t)(b * 16 + h) * 64 * S + kbase0;
  const u16* vP0 = vbase + (size_t)kr0 * S + kcol0;
  const u16* vP1 = vbase + (size_t)kr1 * S + kcol1;

  bf16x8 aq[2][2];
#pragma unroll
  for (int qt = 0; qt < 2; qt++) {
    const u16* qp = Q + ((size_t)(b * S) + q0 + qt * 16 + l16) * E + h * 64;
    aq[qt][0] = *(const bf16x8*)(qp + quad * 8);
    aq[qt][1] = *(const bf16x8*)(qp + 32 + quad * 8);
  }

  const u32* mb = mbits + b * 64;
  const int sx = l16 & 7;
  const int pkey = l16 & 14;

  float lr[2][4] = {};
  f32x4 accO[2][4] = {};
  const float fq0 = (float)(q0 + quad * 4 - 2047);

  const float K1 = 0.125f * 1.44269504f;
  const float K2 = 2.44140625e-4f * 1.44269504f;
  const float K3 = -8.0f * 1.44269504f;

  gload_lds16(kP0, Ks[0] + c0 * 8);
  gload_lds16(kP1, Ks[0] + c1 * 8);
  gload_lds16(vP0, Vs[0] + c0 * 8);
  gload_lds16(vP1, Vs[0] + c1 * 8);
  __syncthreads();

  int buf = 0;
  for (int kc = 0; kc < 1024; kc += 64) {
    if (kc + 64 < 1024) {
      const int kn = kc + 64;
      gload_lds16(kP0 + (size_t)kn * E, Ks[buf ^ 1] + c0 * 8);
      gload_lds16(kP1 + (size_t)kn * E, Ks[buf ^ 1] + c1 * 8);
      gload_lds16(vP0 + kn, Vs[buf ^ 1] + c0 * 8);
      gload_lds16(vP1 + kn, Vs[buf ^ 1] + c1 * 8);
    }
    const u16* ks = Ks[buf];
    const u16* vs = Vs[buf];
    u32* pl = Pl[wave];

    bf16x8 bk[4][2];
#pragma unroll
    for (int T = 0; T < 4; T++)
#pragma unroll
      for (int dh = 0; dh < 2; dh++)
        bk[T][dh] = *(const bf16x8*)(ks + (T * 16 + l16) * 64 +
                                     ((dh * 4 + quad) ^ sx) * 8);

    f32x4 s[2][4] = {};
#pragma unroll
    for (int qt = 0; qt < 2; qt++)
#pragma unroll
      for (int T = 0; T < 4; T++) {
        s[qt][T] = MFMA16(aq[qt][0], bk[T][0], s[qt][T]);
        s[qt][T] = MFMA16(aq[qt][1], bk[T][1], s[qt][T]);
      }

    const int kabs = kbase0 + kc;
    const u64 mw = *(const u64*)(mb + (kabs >> 5));
    const u32 mlo = (u32)mw, mhi = (u32)(mw >> 32);
    const int mk0 = (mlo >> l16) & 1, mk1 = (mlo >> (l16 + 16)) & 1;
    const int mk2 = (mhi >> l16) & 1, mk3 = (mhi >> (l16 + 16)) & 1;
    const float kl = (float)(kabs + l16);

    u32x2 pk1[4];
#pragma unroll
    for (int qt = 0; qt < 2; qt++)
#pragma unroll
      for (int r = 0; r < 4; r++) {
        const float fb = kl + fq0 + (float)(qt * 16 + r);
        const float e0 = fmaf(fabsf(fb), -K2, fmaf(s[qt][0][r], K1, K3));
        const float e1 = fmaf(fabsf(fb + 16.f), -K2, fmaf(s[qt][1][r], K1, K3));
        const float e2 = fmaf(fabsf(fb + 32.f), -K2, fmaf(s[qt][2][r], K1, K3));
        const float e3 = fmaf(fabsf(fb + 48.f), -K2, fmaf(s[qt][3][r], K1, K3));
        const float p0 = mk0 ? 0.f : __builtin_amdgcn_exp2f(e0);
        const float p1 = mk1 ? 0.f : __builtin_amdgcn_exp2f(e1);
        const float p2 = mk2 ? 0.f : __builtin_amdgcn_exp2f(e2);
        const float p3 = mk3 ? 0.f : __builtin_amdgcn_exp2f(e3);
        lr[qt][r] += (p0 + p1) + (p2 + p3);
        u32x2 v;
        v.x = pack_bf2(p0, p1);
        v.y = pack_bf2(p2, p3);
        if (qt == 0) {
          const int m = quad * 4 + r;
          *(u32x2*)(pl + m * 32 + 2 * (l16 ^ (m & 14))) = v;
        } else {
          pk1[r] = v;
        }
      }

    bf16x8 bv[2][4];
#pragma unroll
    for (int kst = 0; kst < 2; kst++)
#pragma unroll
      for (int tt = 0; tt < 4; tt++)
        bv[kst][tt] = *(const bf16x8*)(vs + (tt * 16 + l16) * 64 +
                                       ((kst * 4 + quad) ^ sx) * 8);

    asm volatile("s_waitcnt lgkmcnt(0)" ::: "memory");
    bf16x8 ap0[2];
#pragma unroll
    for (int kst = 0; kst < 2; kst++)
      ap0[kst] = *(const bf16x8*)(pl + l16 * 32 + 2 * ((kst * 8 + 2 * quad) ^ pkey));
#pragma unroll
    for (int kst = 0; kst < 2; kst++)
#pragma unroll
      for (int tt = 0; tt < 4; tt++)
        accO[0][tt] = MFMA16(ap0[kst], bv[kst][tt], accO[0][tt]);

    asm volatile("" ::: "memory");
#pragma unroll
    for (int r = 0; r < 4; r++) {
      const int m = quad * 4 + r;
      *(u32x2*)(pl + m * 32 + 2 * (l16 ^ (m & 14))) = pk1[r];
    }
    asm volatile("s_waitcnt lgkmcnt(0)" ::: "memory");
    bf16x8 ap1[2];
#pragma unroll
    for (int kst = 0; kst < 2; kst++)
      ap1[kst] = *(const bf16x8*)(pl + l16 * 32 + 2 * ((kst * 8 + 2 * quad) ^ pkey));
#pragma unroll
    for (int kst = 0; kst < 2; kst++)
#pragma unroll
      for (int tt = 0; tt < 4; tt++)
        accO[1][tt] = MFMA16(ap1[kst], bv[kst][tt], accO[1][tt]);

    __syncthreads();
    buf ^= 1;
  }

  float* OP = sp ? OP1 : OP0;
#pragma unroll
  for (int qt = 0; qt < 2; qt++)
#pragma unroll
    for (int r = 0; r < 4; r++) {
      float l = lr[qt][r];
      l += __shfl_xor(l, 1);
      l += __shfl_xor(l, 2);
      l += __shfl_xor(l, 4);
      l += __shfl_xor(l, 8);
      const int qg = q0 + qt * 16 + quad * 4 + r;
      const size_t row = ((size_t)bh << 11) + qg;
      float* orow = OP + row * 64;
#pragma unroll
      for (int tt = 0; tt < 4; tt++) orow[tt * 16 + l16] = accO[qt][tt][r];
      if (l16 == 0) Lp[((size_t)sp << 16) + row] = l;
    }
}

// ---------------------------------------------------------------------------
// Merge: Ao[bf16] = (OP0 + OP1) / (l0 + l1), remapped to [B,S,E] layout.
// ---------------------------------------------------------------------------
__global__ __launch_bounds__(256) void attn_merge(const float* __restrict__ OP0,
                                                  const float* __restrict__ OP1,
                                                  const float* __restrict__ Lp,
                                                  u16* __restrict__ Ao) {
  const int i = blockIdx.x * 256 + threadIdx.x;   // over 65536*16
  const int row = i >> 4;
  const int d4 = (i & 15) * 4;
  const float inv = 1.0f / (Lp[row] + Lp[65536 + row]);
  const float4 a = *(const float4*)(OP0 + (size_t)row * 64 + d4);
  const float4 c = *(const float4*)(OP1 + (size_t)row * 64 + d4);
  const int bb = row >> 15, h = (row >> 11) & 15, q = row & 2047;
  u32x2 v;
  v.x = pack_bf2((a.x + c.x) * inv, (a.y + c.y) * inv);
  v.y = pack_bf2((a.z + c.z) * inv, (a.w + c.w) * inv);
  *(u32x2*)(Ao + (size_t)((bb << 11) + q) * 1024 + h * 64 + d4) = v;
}

// ---------------------------------------------------------------------------
extern "C" void kernel_launch(void* const* d_in, const int* in_sizes, int n_in,
                              void* d_out, int out_size, void* d_ws, size_t ws_size,
                              hipStream_t stream) {
  const float* x  = (const float*)d_in[0];
  const float* Wq = (const float*)d_in[1];
  const float* Wk = (const float*)d_in[2];
  const float* Wv = (const float*)d_in[3];
  const float* Wo = (const float*)d_in[4];
  const int* mask = (const int*)d_in[5];

  const int M = 4096, N = 1024, K = 1024;
  const int NE = M * N, NW = N * K;
  const int NB = (NE + 4 * NW) / 2048;

  u16* xb    = (u16*)d_ws;
  u16* Wqkvb = xb + NE;
  u16* Wob   = Wqkvb + (size_t)3 * NW;
  u16* Qb    = Wob + NW;
  u16* Kb    = Qb + NE;
  u16* Vt    = Kb + NE;
  u16* Ao    = Vt + NE;
  u32* mbits = (u32*)(Ao + NE);              // 128 words
  float* OP1 = (float*)(mbits + 128);        // split-1 partials: 16.8 MB
  float* Lp  = OP1 + (size_t)65536 * 64;     // 2 x 65536 row-sums
  float* OP0 = (float*)d_out;                // split-0 partials reuse d_out
                                             // (merge consumes before gemm_out writes)

  cvt_all<<<NB + 1, 256, 0, stream>>>(x, Wq, Wk, Wv, Wo, mask,
                                      xb, Wqkvb, Wob, mbits, NE, NW, NB);

  gemm_qkv<<<dim3(3072 / 128, M / 128), 256, 0, stream>>>(
      xb, Wqkvb, Qb, Kb, Vt, M, 3072, K);
  attn_fwd<<<dim3(16, 32, 2), 256, 0, stream>>>(Qb, Kb, Vt, mbits,
                                                OP0, OP1, Lp);
  attn_merge<<<4096, 256, 0, stream>>>(OP0, OP1, Lp, Ao);
  gemm_out<<<dim3(N / 64, M / 128), 256, 0, stream>>>(
      Ao, Wob, (float*)d_out, M, N, K);
}